// Round 4
// baseline (373.552 us; speedup 1.0000x reference)
//
#include <hip/hip_runtime.h>
#include <hip/hip_bf16.h>

// PIPNet interface scorer: out[p] = W2 . relu(W1 . concat(g1[il[p]], g2[ir[p]]) + b1) + b2
// R4: gather via fire-and-forget global_load_lds (no dest VGPRs -> compiler
// CANNOT serialize; R2/R3's VGPR=52 proved reg-allocator forced one-at-a-time
// loads = 16 full random latencies per wave). f32 tile in LDS (64KB, 2 blk/CU),
// XOR source-swizzle (slice ^ pair&15) to kill unpadded-row bank conflicts,
// f32->bf16 round+v_perm pack fused into the MFMA K-loop.

typedef __bf16 bf16x8 __attribute__((ext_vector_type(8)));
typedef float f32x16 __attribute__((ext_vector_type(16)));

__device__ __forceinline__ unsigned f2bf(float f) {
  union { float f; unsigned u; } v;
  v.f = f;
  unsigned u = v.u;
  return (u + 0x7fffu + ((u >> 16) & 1u)) >> 16;  // RNE
}

// Pre-kernel: W1 [128x128] f32 -> bf16 B-fragments for v_mfma_f32_32x32x16_bf16.
// Fragment (ks, nt, lane): n=lane&31, h=lane>>5; elems = W1[nt*32+n][ks*16+h*8+j]
__global__ __launch_bounds__(256) void w1_frag_kernel(
    const float* __restrict__ W1, uint4* __restrict__ w1f) {
  int t = blockIdx.x * 256 + threadIdx.x;  // 0..2047
  int lane = t & 63;
  int nt = (t >> 6) & 3;
  int ks = t >> 8;
  int n = lane & 31, h = lane >> 5;
  const float4* src =
      (const float4*)(W1 + ((nt * 32 + n) * 128 + ks * 16 + h * 8));
  float4 a = src[0], b = src[1];
  uint4 o;
  o.x = f2bf(a.x) | (f2bf(a.y) << 16);
  o.y = f2bf(a.z) | (f2bf(a.w) << 16);
  o.z = f2bf(b.x) | (f2bf(b.y) << 16);
  o.w = f2bf(b.z) | (f2bf(b.w) << 16);
  w1f[t] = o;
}

__global__ __launch_bounds__(256, 2) void pip_main_kernel(
    const float* __restrict__ g1, const float* __restrict__ g2,
    const int* __restrict__ il, const int* __restrict__ ir,
    const bf16x8* __restrict__ w1f,
    const float* __restrict__ b1, const float* __restrict__ w2,
    const float* __restrict__ b2,
    float* __restrict__ out, int P) {
  // Tile: 128 pairs x 128 f32 (left 64 || right 64) = 64 KB.
  // Storage is (pair,side)-row granular: row R = p*2+side, 64 floats.
  // Physical slice layout within a row: phys = logical ^ (p & 15)  [16B slices]
  __shared__ float T[128 * 128];

  const int t = threadIdx.x;
  const int lane = t & 63;
  const int w = t >> 6;
  const int pair0 = blockIdx.x * 128;

  // ---- Stage: 16 rounds, each wave pulls 4 rows (1 KB) via global_load_lds ----
  // lane -> (g = lane>>4) row within the wave's 4-row group; dest = base+lane*16.
  const int sl = lane & 15;        // physical 16B slice this lane fills
  const int g = lane >> 4;
  const int side = g & 1;          // 0: left/g1, 1: right/g2 (fixed per thread)
  const int halfg = lane >> 5;
  const float* feat = side ? g2 : g1;
  const int* idxarr = side ? ir : il;
  const int plocB = w * 2 + halfg;

  int idxv[16];
#pragma unroll
  for (int j = 0; j < 16; ++j) {
    int gp = pair0 + j * 8 + plocB;
    int pidx = (gp < P) ? gp : (P - 1);
    idxv[j] = idxarr[pidx];
  }
#pragma unroll
  for (int j = 0; j < 16; ++j) {
    int ploc = j * 8 + plocB;
    // source: logical slice (sl ^ ploc&15) of the gathered row
    const float* src = feat + (size_t)idxv[j] * 64 + ((sl ^ ploc) & 15) * 4;
    float* dst = &T[(j * 16 + w * 4) * 64];  // wave-uniform base (rows R0..R0+3)
    __builtin_amdgcn_global_load_lds(
        (const __attribute__((address_space(1))) unsigned int*)src,
        (__attribute__((address_space(3))) unsigned int*)dst, 16, 0, 0);
  }
  __syncthreads();  // drains vmcnt -> all LDS rows valid

  // ---- Compute: wave w -> pairs [w*32, w*32+32), n = 0..127 ----
  const int n = lane & 31;
  const int h = lane >> 5;
  const int p = w * 32 + n;      // local pair
  const int key = p & 15;        // de-swizzle key
  const uint4* As = (const uint4*)T;
  const int rowbase = p * 32;    // uint4 units: (p*2 rows) * 16 slices

  f32x16 acc[4];
#pragma unroll
  for (int nt = 0; nt < 4; ++nt)
#pragma unroll
    for (int i = 0; i < 16; ++i) acc[nt][i] = 0.0f;

#pragma unroll
  for (int ks = 0; ks < 8; ++ks) {
    const int sideK = ks >> 2;
    const int s0 = (ks & 3) * 4 + h * 2;      // even logical slice
    const int base = rowbase + sideK * 16;
    uint4 lo = As[base + (s0 ^ key)];          // k = ks*16+h*8 + 0..3 (f32 bits)
    uint4 hi = As[base + ((s0 + 1) ^ key)];    // k = ks*16+h*8 + 4..7
    // round (+0x8000) and pack hi16 pairs with v_perm_b32
    union { unsigned u[4]; bf16x8 v; } fr;
    fr.u[0] = __builtin_amdgcn_perm(lo.y + 0x8000u, lo.x + 0x8000u, 0x07060302u);
    fr.u[1] = __builtin_amdgcn_perm(lo.w + 0x8000u, lo.z + 0x8000u, 0x07060302u);
    fr.u[2] = __builtin_amdgcn_perm(hi.y + 0x8000u, hi.x + 0x8000u, 0x07060302u);
    fr.u[3] = __builtin_amdgcn_perm(hi.w + 0x8000u, hi.z + 0x8000u, 0x07060302u);
#pragma unroll
    for (int nt = 0; nt < 4; ++nt) {
      bf16x8 bfr = w1f[(ks * 4 + nt) * 64 + lane];
      acc[nt] = __builtin_amdgcn_mfma_f32_32x32x16_bf16(fr.v, bfr, acc[nt], 0, 0, 0);
    }
  }

  // ---- Epilogue: out[p] = sum_n relu(acc + b1[n]) * w2[n] + b2 ----
  // C/D layout: col(n) = lane&31 (+32*nt), row(m) = (r&3) + 8*(r>>2) + 4*h.
  float b1v[4], w2v[4];
#pragma unroll
  for (int nt = 0; nt < 4; ++nt) {
    b1v[nt] = b1[nt * 32 + n];
    w2v[nt] = w2[nt * 32 + n];
  }
  const float bias2 = b2[0];

#pragma unroll
  for (int r = 0; r < 16; ++r) {
    float s = 0.0f;
#pragma unroll
    for (int nt = 0; nt < 4; ++nt) {
      float vv = acc[nt][r] + b1v[nt];
      vv = fmaxf(vv, 0.0f);
      s = fmaf(vv, w2v[nt], s);
    }
    s += __shfl_xor(s, 1);
    s += __shfl_xor(s, 2);
    s += __shfl_xor(s, 4);
    s += __shfl_xor(s, 8);
    s += __shfl_xor(s, 16);
    if (n == 0) {
      int row = (r & 3) + 8 * (r >> 2) + 4 * h;
      int gp = pair0 + w * 32 + row;
      if (gp < P) out[gp] = s + bias2;
    }
  }
}

extern "C" void kernel_launch(void* const* d_in, const int* in_sizes, int n_in,
                              void* d_out, int out_size, void* d_ws, size_t ws_size,
                              hipStream_t stream) {
  const float* g1 = (const float*)d_in[0];   // graph1_x [N,64] f32
  const float* g2 = (const float*)d_in[1];   // graph2_x [N,64] f32
  const int* il = (const int*)d_in[2];       // idx_left [P] int32
  const int* ir = (const int*)d_in[3];       // idx_right [P] int32
  const float* W1 = (const float*)d_in[4];   // [128,128]
  const float* b1 = (const float*)d_in[5];   // [128]
  const float* w2 = (const float*)d_in[6];   // [1,128]
  const float* b2 = (const float*)d_in[7];   // [1]
  float* out = (float*)d_out;                // [P,1] f32
  const int P = out_size;

  // d_ws: 32 KB of bf16 W1 B-fragments (rebuilt every call; ws is re-poisoned)
  w1_frag_kernel<<<8, 256, 0, stream>>>(W1, (uint4*)d_ws);

  const int nblocks = (P + 127) / 128;
  pip_main_kernel<<<nblocks, 256, 0, stream>>>(
      g1, g2, il, ir, (const bf16x8*)d_ws, b1, w2, b2, out, P);
}

// Round 6
// 339.322 us; speedup vs baseline: 1.1009x; 1.1009x over previous
//
#include <hip/hip_runtime.h>
#include <hip/hip_bf16.h>

// PIPNet interface scorer: out[p] = W2 . relu(W1 . concat(g1[il[p]], g2[ir[p]]) + b1) + b2
// R6 = R5 with compilable liveness pins: LLVM rejects tied ("+v") vector-typed
// asm operands, so pin the 32 scalar components instead. Goal unchanged: force
// 8 gather loads to be simultaneously in flight (R2/R3's VGPR=52 proved the
// reg-allocator serialized them => 32 dependent random latencies per wave).

typedef __bf16 bf16x8 __attribute__((ext_vector_type(8)));
typedef float f32x16 __attribute__((ext_vector_type(16)));

__device__ __forceinline__ unsigned f2bf(float f) {
  union { float f; unsigned u; } v;
  v.f = f;
  unsigned u = v.u;
  return (u + 0x7fffu + ((u >> 16) & 1u)) >> 16;  // RNE
}

// Pre-kernel: W1 [128x128] f32 -> bf16 B-fragments for v_mfma_f32_32x32x16_bf16.
// Fragment (ks, nt, lane): n=lane&31, h=lane>>5; elems = W1[nt*32+n][ks*16+h*8+j]
__global__ __launch_bounds__(256) void w1_frag_kernel(
    const float* __restrict__ W1, uint4* __restrict__ w1f) {
  int t = blockIdx.x * 256 + threadIdx.x;  // 0..2047
  int lane = t & 63;
  int nt = (t >> 6) & 3;
  int ks = t >> 8;
  int n = lane & 31, h = lane >> 5;
  const float4* src =
      (const float4*)(W1 + ((nt * 32 + n) * 128 + ks * 16 + h * 8));
  float4 a = src[0], b = src[1];
  uint4 o;
  o.x = f2bf(a.x) | (f2bf(a.y) << 16);
  o.y = f2bf(a.z) | (f2bf(a.w) << 16);
  o.z = f2bf(b.x) | (f2bf(b.y) << 16);
  o.w = f2bf(b.z) | (f2bf(b.w) << 16);
  w1f[t] = o;
}

#define LDS_STRIDE 136  // shorts; 272B rows, 16B-aligned, zero bank conflicts

__global__ __launch_bounds__(256, 3) void pip_main_kernel(
    const float* __restrict__ g1, const float* __restrict__ g2,
    const int* __restrict__ il, const int* __restrict__ ir,
    const bf16x8* __restrict__ w1f,
    const float* __restrict__ b1, const float* __restrict__ w2,
    const float* __restrict__ b2,
    float* __restrict__ out, int P) {
  __shared__ unsigned short A[128 * LDS_STRIDE];  // 34,816 B

  const int t = threadIdx.x;
  const int lane = t & 63;
  const int w = t >> 6;
  const int pair0 = blockIdx.x * 128;

  // ---- Cooperative gather: 16 lanes per (pair,side) row of 64 floats ----
  const int sub = lane & 15;          // lane's 16B slice within the row
  const int g = lane >> 4;
  const int side = g & 1;             // 0: left/g1, 1: right/g2 (fixed)
  const int pairB = w * 2 + (g >> 1); // 0..7
  const float* feat = side ? g2 : g1;
  const int* idxarr = side ? ir : il;

  // Phase 1: all 16 index loads in flight together
  int idxv[16];
#pragma unroll
  for (int j = 0; j < 16; ++j) {
    int gp = pair0 + j * 8 + pairB;
    int pidx = (gp < P) ? gp : (P - 1);
    idxv[j] = idxarr[pidx];
  }
  asm volatile("" : "+v"(idxv[0]), "+v"(idxv[1]), "+v"(idxv[2]), "+v"(idxv[3]),
                    "+v"(idxv[4]), "+v"(idxv[5]), "+v"(idxv[6]), "+v"(idxv[7]),
                    "+v"(idxv[8]), "+v"(idxv[9]), "+v"(idxv[10]), "+v"(idxv[11]),
                    "+v"(idxv[12]), "+v"(idxv[13]), "+v"(idxv[14]), "+v"(idxv[15]));

  // Phase 2: two batches of 8 row gathers, forced concurrent by liveness pin
  // (scalar-component pins — tied vector asm operands don't compile)
#pragma unroll
  for (int b = 0; b < 2; ++b) {
    float4 v[8];
#pragma unroll
    for (int u = 0; u < 8; ++u)
      v[u] = *(const float4*)(feat + (size_t)idxv[b * 8 + u] * 64 + sub * 4);
    asm volatile("" :
        "+v"(v[0].x), "+v"(v[0].y), "+v"(v[0].z), "+v"(v[0].w),
        "+v"(v[1].x), "+v"(v[1].y), "+v"(v[1].z), "+v"(v[1].w),
        "+v"(v[2].x), "+v"(v[2].y), "+v"(v[2].z), "+v"(v[2].w),
        "+v"(v[3].x), "+v"(v[3].y), "+v"(v[3].z), "+v"(v[3].w),
        "+v"(v[4].x), "+v"(v[4].y), "+v"(v[4].z), "+v"(v[4].w),
        "+v"(v[5].x), "+v"(v[5].y), "+v"(v[5].z), "+v"(v[5].w),
        "+v"(v[6].x), "+v"(v[6].y), "+v"(v[6].z), "+v"(v[6].w),
        "+v"(v[7].x), "+v"(v[7].y), "+v"(v[7].z), "+v"(v[7].w));
#pragma unroll
    for (int u = 0; u < 8; ++u) {
      int j = b * 8 + u;
      unsigned lo = f2bf(v[u].x) | (f2bf(v[u].y) << 16);
      unsigned hi = f2bf(v[u].z) | (f2bf(v[u].w) << 16);
      *(uint2*)(A + (j * 8 + pairB) * LDS_STRIDE + side * 64 + sub * 4) =
          make_uint2(lo, hi);
    }
  }
  __syncthreads();

  // ---- Compute: wave w handles pairs [w*32, w*32+32), n = 0..127 ----
  const int n = lane & 31;
  const int h = lane >> 5;

  f32x16 acc[4];
#pragma unroll
  for (int nt = 0; nt < 4; ++nt)
#pragma unroll
    for (int i = 0; i < 16; ++i) acc[nt][i] = 0.0f;

  const unsigned short* Arow = A + (w * 32 + n) * LDS_STRIDE + h * 8;
#pragma unroll
  for (int ks = 0; ks < 8; ++ks) {
    bf16x8 af = *(const bf16x8*)(Arow + ks * 16);
#pragma unroll
    for (int nt = 0; nt < 4; ++nt) {
      bf16x8 bfr = w1f[(ks * 4 + nt) * 64 + lane];
      acc[nt] = __builtin_amdgcn_mfma_f32_32x32x16_bf16(af, bfr, acc[nt], 0, 0, 0);
    }
  }

  // ---- Epilogue: out[p] = sum_n relu(acc + b1[n]) * w2[n] + b2 ----
  // C/D layout: col(n) = lane&31 (+32*nt), row(m) = (r&3) + 8*(r>>2) + 4*h.
  float b1v[4], w2v[4];
#pragma unroll
  for (int nt = 0; nt < 4; ++nt) {
    b1v[nt] = b1[nt * 32 + n];
    w2v[nt] = w2[nt * 32 + n];
  }
  const float bias2 = b2[0];

#pragma unroll
  for (int r = 0; r < 16; ++r) {
    float s = 0.0f;
#pragma unroll
    for (int nt = 0; nt < 4; ++nt) {
      float vv = acc[nt][r] + b1v[nt];
      vv = fmaxf(vv, 0.0f);
      s = fmaf(vv, w2v[nt], s);
    }
    s += __shfl_xor(s, 1);
    s += __shfl_xor(s, 2);
    s += __shfl_xor(s, 4);
    s += __shfl_xor(s, 8);
    s += __shfl_xor(s, 16);
    if (n == 0) {
      int row = (r & 3) + 8 * (r >> 2) + 4 * h;
      int gp = pair0 + w * 32 + row;
      if (gp < P) out[gp] = s + bias2;
    }
  }
}

extern "C" void kernel_launch(void* const* d_in, const int* in_sizes, int n_in,
                              void* d_out, int out_size, void* d_ws, size_t ws_size,
                              hipStream_t stream) {
  const float* g1 = (const float*)d_in[0];   // graph1_x [N,64] f32
  const float* g2 = (const float*)d_in[1];   // graph2_x [N,64] f32
  const int* il = (const int*)d_in[2];       // idx_left [P] int32
  const int* ir = (const int*)d_in[3];       // idx_right [P] int32
  const float* W1 = (const float*)d_in[4];   // [128,128]
  const float* b1 = (const float*)d_in[5];   // [128]
  const float* w2 = (const float*)d_in[6];   // [1,128]
  const float* b2 = (const float*)d_in[7];   // [1]
  float* out = (float*)d_out;                // [P,1] f32
  const int P = out_size;

  // d_ws: 32 KB of bf16 W1 B-fragments (rebuilt every call; ws is re-poisoned)
  w1_frag_kernel<<<8, 256, 0, stream>>>(W1, (uint4*)d_ws);

  const int nblocks = (P + 127) / 128;
  pip_main_kernel<<<nblocks, 256, 0, stream>>>(
      g1, g2, il, ir, (const bf16x8*)d_ws, b1, w2, b2, out, P);
}